// Round 9
// baseline (400.228 us; speedup 1.0000x reference)
//
#include <hip/hip_runtime.h>
#include <math.h>

#define N_NODES 100000
#define N_EDGES 1600000
#define NBUCK 391          // ceil(100000 / 256)
#define BSTRIDE 4608       // bucket slack stride: mean 4096 + 8 sigma
#define CSLICE ((N_NODES + 1) * 16)   // chunk-major slice stride (fp16 elems)

typedef __attribute__((ext_vector_type(8))) _Float16 h8v;
typedef __attribute__((ext_vector_type(2))) _Float16 h2v;
typedef __attribute__((ext_vector_type(4))) float f32x4;

// ---------------- CSR build: 2 kernels + 1 memset ----------------

__launch_bounds__(256)
__global__ void k_bpart(const int* __restrict__ srcv, const int* __restrict__ dstv,
                        int* __restrict__ bcnt, unsigned int* __restrict__ ebuf) {
    __shared__ int hist[NBUCK];
    __shared__ int cur[NBUCK];
    const int tid = threadIdx.x;
    for (int t = tid; t < NBUCK; t += 256) hist[t] = 0;
    __syncthreads();
    const int base = blockIdx.x * 4096;
#pragma unroll
    for (int i = 0; i < 16; i++) {
        int e = base + i * 256 + tid;
        if (e < N_EDGES) atomicAdd(&hist[dstv[e] >> 8], 1);
    }
    __syncthreads();
    for (int t = tid; t < NBUCK; t += 256)
        if (hist[t]) cur[t] = t * BSTRIDE + atomicAdd(&bcnt[t], hist[t]);
    __syncthreads();
#pragma unroll
    for (int i = 0; i < 16; i++) {
        int e = base + i * 256 + tid;
        if (e < N_EDGES) {
            int d = dstv[e];
            int p = atomicAdd(&cur[d >> 8], 1);
            ebuf[p] = ((unsigned int)srcv[e] << 8) | (unsigned int)(d & 255);
        }
    }
}

__launch_bounds__(256)
__global__ void k_bucket(const unsigned int* __restrict__ ebuf, const int* __restrict__ bcnt,
                         int2* __restrict__ rowse, float* __restrict__ dinv,
                         int* __restrict__ colidx) {
    __shared__ int cnt[256];
    __shared__ int s[256];
    __shared__ int cur[256];
    const int tid = threadIdx.x;
    const int b = blockIdx.x;
    const int e0 = b * BSTRIDE;
    const int e1 = e0 + bcnt[b];
    cnt[tid] = 0;
    __syncthreads();
    for (int e = e0 + tid; e < e1; e += 256) atomicAdd(&cnt[ebuf[e] & 255u], 1);
    __syncthreads();
    int v = cnt[tid];
    int x = v;
    s[tid] = x;
    __syncthreads();
    for (int d = 1; d < 256; d <<= 1) {
        int t = (tid >= d) ? s[tid - d] : 0;
        __syncthreads();
        x += t;
        s[tid] = x;
        __syncthreads();
    }
    int start = e0 + x - v;
    int node = b * 256 + tid;
    if (node < N_NODES) {
        rowse[node] = make_int2(start, start + v);
        dinv[node] = rsqrtf((float)(v + 1));  // +1 self-loop
    }
    cur[tid] = start;
    __syncthreads();
    for (int e = e0 + tid; e < e1; e += 256) {
        unsigned int sd = ebuf[e];
        int pos = atomicAdd(&cur[sd & 255u], 1);
        colidx[pos] = (int)(sd >> 8);
    }
}

// Zero sentinel rows: bufC chunk-major (8 x 16), bufA row-major (128), zbuf (64).
__global__ void k_zrows(_Float16* __restrict__ bufC, _Float16* __restrict__ bufA,
                        _Float16* __restrict__ zbuf) {
    int t = threadIdx.x;
    if (t < 128) bufC[(size_t)(t >> 4) * CSLICE + (size_t)N_NODES * 16 + (t & 15)] = (_Float16)0.f;
    if (t < 128) bufA[(size_t)N_NODES * 128 + t] = (_Float16)0.f;
    if (t < 64)  zbuf[(size_t)N_NODES * 64 + t] = (_Float16)0.f;
}

// ---------------- fused weight prep ----------------

__global__ void k_wprep_all(const float* __restrict__ W1, const float* __restrict__ W2,
                            const float* __restrict__ W3, _Float16* __restrict__ Wt) {
    int idx = blockIdx.x * blockDim.x + threadIdx.x;
    if (idx >= 304 * 128) return;
    int n = idx / 128, k = idx % 128;
    const float* W;
    int ncols, nloc;
    _Float16 *ph, *pl;
    if (n < 128)      { W = W1; ncols = 128; nloc = n;       ph = Wt;                 pl = Wt + 128 * 128; }
    else if (n < 256) { W = W2; ncols = 128; nloc = n - 128; ph = Wt + 2 * 128 * 128; pl = Wt + 3 * 128 * 128; }
    else              { W = W3; ncols = 40;  nloc = n - 256; ph = Wt + 4 * 128 * 128; pl = Wt + 4 * 128 * 128 + 48 * 128; }
    float v = (nloc < ncols) ? W[k * ncols + nloc] : 0.f;
    _Float16 hi = (_Float16)v;
    _Float16 lo = (_Float16)(v - (float)hi);
    ph[nloc * 128 + k] = hi;
    pl[nloc * 128 + k] = lo;
}

// ---------------- Persistent-B MFMA GEMMs ----------------

#define GEMM_GRID 625
#define NTILES 3125

// Layer 1: fp32 A, CHUNK-MAJOR output [8][N+1][16].
__launch_bounds__(256, 2)
__global__ void k_gemm128_f32(const float* __restrict__ Af,
                              const _Float16* __restrict__ Wthi, const _Float16* __restrict__ Wtlo,
                              const float* __restrict__ dinv, _Float16* __restrict__ out) {
    const int lane = threadIdx.x & 63;
    const int wi = threadIdx.x >> 6;
    const int nb = wi * 32;
    const int nn = lane & 15;
    const int kq = (lane >> 4) * 8;
    const int quad = lane >> 4;

    h8v bh[4][2], bl[4][2];
#pragma unroll
    for (int c = 0; c < 4; c++)
#pragma unroll
        for (int t = 0; t < 2; t++) {
            int off = (nb + t * 16 + nn) * 128 + c * 32 + kq;
            bh[c][t] = *(const h8v*)(Wthi + off);
            bl[c][t] = *(const h8v*)(Wtlo + off);
        }

    for (int rt = blockIdx.x; rt < NTILES; rt += GEMM_GRID) {
        const int r0 = rt * 32;
        f32x4 acc[2][2] = {};
#pragma unroll
        for (int c = 0; c < 4; c++) {
            h8v a[2];
#pragma unroll
            for (int m = 0; m < 2; m++) {
                const float* p = Af + (size_t)(r0 + m * 16 + nn) * 128 + c * 32 + kq;
                float4 p0 = *(const float4*)p;
                float4 p1 = *(const float4*)(p + 4);
                h8v av = {(_Float16)p0.x, (_Float16)p0.y, (_Float16)p0.z, (_Float16)p0.w,
                          (_Float16)p1.x, (_Float16)p1.y, (_Float16)p1.z, (_Float16)p1.w};
                a[m] = av;
            }
#pragma unroll
            for (int m = 0; m < 2; m++)
#pragma unroll
                for (int t = 0; t < 2; t++) {
                    acc[m][t] = __builtin_amdgcn_mfma_f32_16x16x32_f16(a[m], bh[c][t], acc[m][t], 0, 0, 0);
                    acc[m][t] = __builtin_amdgcn_mfma_f32_16x16x32_f16(a[m], bl[c][t], acc[m][t], 0, 0, 0);
                }
        }
#pragma unroll
        for (int m = 0; m < 2; m++)
#pragma unroll
            for (int reg = 0; reg < 4; reg++) {
                int r = r0 + m * 16 + quad * 4 + reg;
                float dv = dinv[r];
#pragma unroll
                for (int t = 0; t < 2; t++)
                    out[(size_t)(wi * 2 + t) * CSLICE + (size_t)r * 16 + nn] =
                        (_Float16)(acc[m][t][reg] * dv);
            }
    }
}

// Layer 2: fp16 A, row-major output.
__launch_bounds__(256, 2)
__global__ void k_gemm128(const _Float16* __restrict__ A,
                          const _Float16* __restrict__ Wthi, const _Float16* __restrict__ Wtlo,
                          const float* __restrict__ dinv, _Float16* __restrict__ out) {
    const int lane = threadIdx.x & 63;
    const int wi = threadIdx.x >> 6;
    const int nb = wi * 32;
    const int nn = lane & 15;
    const int kq = (lane >> 4) * 8;
    const int quad = lane >> 4;

    h8v bh[4][2], bl[4][2];
#pragma unroll
    for (int c = 0; c < 4; c++)
#pragma unroll
        for (int t = 0; t < 2; t++) {
            int off = (nb + t * 16 + nn) * 128 + c * 32 + kq;
            bh[c][t] = *(const h8v*)(Wthi + off);
            bl[c][t] = *(const h8v*)(Wtlo + off);
        }

    for (int rt = blockIdx.x; rt < NTILES; rt += GEMM_GRID) {
        const int r0 = rt * 32;
        f32x4 acc[2][2] = {};
#pragma unroll
        for (int c = 0; c < 4; c++) {
            h8v a[2];
#pragma unroll
            for (int m = 0; m < 2; m++)
                a[m] = *(const h8v*)(A + (size_t)(r0 + m * 16 + nn) * 128 + c * 32 + kq);
#pragma unroll
            for (int m = 0; m < 2; m++)
#pragma unroll
                for (int t = 0; t < 2; t++) {
                    acc[m][t] = __builtin_amdgcn_mfma_f32_16x16x32_f16(a[m], bh[c][t], acc[m][t], 0, 0, 0);
                    acc[m][t] = __builtin_amdgcn_mfma_f32_16x16x32_f16(a[m], bl[c][t], acc[m][t], 0, 0, 0);
                }
        }
#pragma unroll
        for (int m = 0; m < 2; m++)
#pragma unroll
            for (int reg = 0; reg < 4; reg++) {
                int r = r0 + m * 16 + quad * 4 + reg;
                float dv = dinv[r];
#pragma unroll
                for (int t = 0; t < 2; t++)
                    out[(size_t)r * 128 + nb + t * 16 + nn] = (_Float16)(acc[m][t][reg] * dv);
            }
    }
}

// Layer-3 GEMM: 40 real cols (48 written) into [N+1][64]-stride buffer.
#define G40_GRID 160

__launch_bounds__(256, 2)
__global__ void k_gemm40(const _Float16* __restrict__ A,
                         const _Float16* __restrict__ Wthi, const _Float16* __restrict__ Wtlo,
                         const float* __restrict__ dinv, _Float16* __restrict__ out) {
    const int lane = threadIdx.x & 63;
    const int wi = threadIdx.x >> 6;
    const int nn = lane & 15;
    const int kq = (lane >> 4) * 8;
    const int quad = lane >> 4;

    h8v bh[4][3], bl[4][3];
#pragma unroll
    for (int c = 0; c < 4; c++)
#pragma unroll
        for (int t = 0; t < 3; t++) {
            int off = (t * 16 + nn) * 128 + c * 32 + kq;
            bh[c][t] = *(const h8v*)(Wthi + off);
            bl[c][t] = *(const h8v*)(Wtlo + off);
        }

    for (int rt = blockIdx.x * 4 + wi; rt < NTILES; rt += G40_GRID * 4) {
        const int r0 = rt * 32;
        f32x4 acc[2][3] = {};
#pragma unroll
        for (int c = 0; c < 4; c++) {
            h8v a[2];
#pragma unroll
            for (int m = 0; m < 2; m++)
                a[m] = *(const h8v*)(A + (size_t)(r0 + m * 16 + nn) * 128 + c * 32 + kq);
#pragma unroll
            for (int m = 0; m < 2; m++)
#pragma unroll
                for (int t = 0; t < 3; t++) {
                    acc[m][t] = __builtin_amdgcn_mfma_f32_16x16x32_f16(a[m], bh[c][t], acc[m][t], 0, 0, 0);
                    acc[m][t] = __builtin_amdgcn_mfma_f32_16x16x32_f16(a[m], bl[c][t], acc[m][t], 0, 0, 0);
                }
        }
#pragma unroll
        for (int m = 0; m < 2; m++)
#pragma unroll
            for (int reg = 0; reg < 4; reg++) {
                int r = r0 + m * 16 + quad * 4 + reg;
                float dv = dinv[r];
#pragma unroll
                for (int t = 0; t < 3; t++)
                    out[(size_t)r * 64 + t * 16 + nn] = (_Float16)(acc[m][t][reg] * dv);
            }
    }
}

// ---------------- XCD-pinned chunked aggregation (layer 1) ----------------
// hp chunk-major [8][N+1][16]; chunk = blockIdx % 8 pins each 3.2MB slice to
// one XCD's L2 (round-robin dispatch). Wave = 8 row-slots x 8 lanes x 4B.
// Output row-major [N][128] (+bias+relu).

__launch_bounds__(256)
__global__ void k_aggc(const _Float16* __restrict__ hp, const int2* __restrict__ rowse,
                       const int* __restrict__ colidx, const float* __restrict__ bias,
                       _Float16* __restrict__ outp) {
    const int lane = threadIdx.x & 63;
    const int wv = threadIdx.x >> 6;
    const int chunk = blockIdx.x & 7;
    const int rb = blockIdx.x >> 3;       // 0..3124
    const int rs = lane >> 3;             // row slot 0..7
    const int cp = lane & 7;              // 4B col-pair
    const int r = rb * 32 + wv * 8 + rs;

    const int2 se = rowse[r];
    const int deg = se.y - se.x;
    int m = deg;
    m = max(m, __shfl_xor(m, 8));
    m = max(m, __shfl_xor(m, 16));
    m = max(m, __shfl_xor(m, 32));

    const _Float16* base = hp + (size_t)chunk * CSLICE + cp * 2;
    h2v acc = {};
    for (int it = 0; it < m; it += 4) {
        int i0 = se.x + it;
        int s0 = colidx[i0];
        int s1 = colidx[i0 + 1];
        int s2 = colidx[i0 + 2];
        int s3 = colidx[i0 + 3];
        s0 = (it < deg) ? s0 : N_NODES;
        s1 = (it + 1 < deg) ? s1 : N_NODES;
        s2 = (it + 2 < deg) ? s2 : N_NODES;
        s3 = (it + 3 < deg) ? s3 : N_NODES;
        h2v v0 = *(const h2v*)(base + (size_t)s0 * 16);
        h2v v1 = *(const h2v*)(base + (size_t)s1 * 16);
        h2v v2 = *(const h2v*)(base + (size_t)s2 * 16);
        h2v v3 = *(const h2v*)(base + (size_t)s3 * 16);
        acc += v0;
        acc += v1;
        acc += v2;
        acc += v3;
    }

    h2v sv = *(const h2v*)(base + (size_t)r * 16);  // self-loop
    float dv = rsqrtf((float)(deg + 1));
    float2 b = *(const float2*)(bias + chunk * 16 + cp * 2);
    float ox = fmaxf(fmaf(dv, (float)acc.x + (float)sv.x, b.x), 0.f);
    float oy = fmaxf(fmaf(dv, (float)acc.y + (float)sv.y, b.y), 0.f);
    h2v o = {(_Float16)ox, (_Float16)oy};
    *(h2v*)(outp + (size_t)r * 128 + chunk * 16 + cp * 2) = o;
}

// ---------------- Slot-parallel aggregation (layer 2, row-major control) ----------------

__launch_bounds__(256)
__global__ void k_agg4(const _Float16* __restrict__ hp, const int2* __restrict__ rowse,
                       const int* __restrict__ colidx, const float* __restrict__ bias,
                       _Float16* __restrict__ outp) {
    const int lane = threadIdx.x & 63;
    const int wid = (blockIdx.x * blockDim.x + threadIdx.x) >> 6;
    const int rs = lane >> 4;   // row slot 0..3
    const int cp = lane & 15;   // 16B col part
    const int r = wid * 4 + rs;

    const int2 se = rowse[r];
    const int deg = se.y - se.x;
    int m = deg;
    m = max(m, __shfl_xor(m, 16));
    m = max(m, __shfl_xor(m, 32));

    const _Float16* hpc = hp + cp * 8;
    h8v acc = {};
    for (int it = 0; it < m; it += 4) {
        int i0 = se.x + it;
        int s0 = colidx[i0];
        int s1 = colidx[i0 + 1];
        int s2 = colidx[i0 + 2];
        int s3 = colidx[i0 + 3];
        s0 = (it < deg) ? s0 : N_NODES;
        s1 = (it + 1 < deg) ? s1 : N_NODES;
        s2 = (it + 2 < deg) ? s2 : N_NODES;
        s3 = (it + 3 < deg) ? s3 : N_NODES;
        h8v v0 = *(const h8v*)(hpc + (size_t)s0 * 128);
        h8v v1 = *(const h8v*)(hpc + (size_t)s1 * 128);
        h8v v2 = *(const h8v*)(hpc + (size_t)s2 * 128);
        h8v v3 = *(const h8v*)(hpc + (size_t)s3 * 128);
        acc += v0;
        acc += v1;
        acc += v2;
        acc += v3;
    }

    h8v sv = *(const h8v*)(hpc + (size_t)r * 128);  // self-loop
    float dv = rsqrtf((float)(deg + 1));
    const float* bp = bias + cp * 8;
    float4 b0 = *(const float4*)bp;
    float4 b1 = *(const float4*)(bp + 4);
    float bb[8] = {b0.x, b0.y, b0.z, b0.w, b1.x, b1.y, b1.z, b1.w};
    h8v o;
#pragma unroll
    for (int j = 0; j < 8; j++) {
        float s = (float)acc[j] + (float)sv[j];
        o[j] = (_Float16)fmaxf(fmaf(dv, s, bb[j]), 0.f);
    }
    *(h8v*)(outp + (size_t)r * 128 + cp * 8) = o;
}

// ---------------- Final aggregation (64-stride rows) + fused log_softmax ----------------

__launch_bounds__(256)
__global__ void k_agg_out(const _Float16* __restrict__ hp, const int2* __restrict__ rowse,
                          const int* __restrict__ colidx, float* __restrict__ out) {
    const int lane = threadIdx.x & 63;
    const int wid = (blockIdx.x * blockDim.x + threadIdx.x) >> 6;
    const int rs = lane >> 3;   // row slot 0..7
    const int cp = lane & 7;    // 16B col part
    const int r = wid * 8 + rs;

    const int2 se = rowse[r];
    const int deg = se.y - se.x;
    int m = deg;
    m = max(m, __shfl_xor(m, 8));
    m = max(m, __shfl_xor(m, 16));
    m = max(m, __shfl_xor(m, 32));

    const _Float16* hpc = hp + cp * 8;
    h8v acc = {};
    for (int it = 0; it < m; it += 4) {
        int i0 = se.x + it;
        int s0 = colidx[i0];
        int s1 = colidx[i0 + 1];
        int s2 = colidx[i0 + 2];
        int s3 = colidx[i0 + 3];
        s0 = (it < deg) ? s0 : N_NODES;
        s1 = (it + 1 < deg) ? s1 : N_NODES;
        s2 = (it + 2 < deg) ? s2 : N_NODES;
        s3 = (it + 3 < deg) ? s3 : N_NODES;
        h8v v0 = *(const h8v*)(hpc + (size_t)s0 * 64);
        h8v v1 = *(const h8v*)(hpc + (size_t)s1 * 64);
        h8v v2 = *(const h8v*)(hpc + (size_t)s2 * 64);
        h8v v3 = *(const h8v*)(hpc + (size_t)s3 * 64);
        acc += v0;
        acc += v1;
        acc += v2;
        acc += v3;
    }

    h8v sv = *(const h8v*)(hpc + (size_t)r * 64);  // self-loop
    float dv = rsqrtf((float)(deg + 1));
    float z[8];
#pragma unroll
    for (int j = 0; j < 8; j++) z[j] = dv * ((float)acc[j] + (float)sv[j]);

    const bool act = cp < 5;  // cols 0..39
    float pm = -INFINITY;
    if (act) {
#pragma unroll
        for (int j = 0; j < 8; j++) pm = fmaxf(pm, z[j]);
    }
    pm = fmaxf(pm, __shfl_xor(pm, 1));
    pm = fmaxf(pm, __shfl_xor(pm, 2));
    pm = fmaxf(pm, __shfl_xor(pm, 4));
    float pe = 0.f;
    if (act) {
#pragma unroll
        for (int j = 0; j < 8; j++) pe += __expf(z[j] - pm);
    }
    pe += __shfl_xor(pe, 1);
    pe += __shfl_xor(pe, 2);
    pe += __shfl_xor(pe, 4);
    float lse = __logf(pe);
    if (act) {
        float* po = out + (size_t)r * 40 + cp * 8;
        float4 o0 = make_float4(z[0] - pm - lse, z[1] - pm - lse, z[2] - pm - lse, z[3] - pm - lse);
        float4 o1 = make_float4(z[4] - pm - lse, z[5] - pm - lse, z[6] - pm - lse, z[7] - pm - lse);
        *(float4*)po = o0;
        *(float4*)(po + 4) = o1;
    }
}

// ---------------- launch ----------------

extern "C" void kernel_launch(void* const* d_in, const int* in_sizes, int n_in,
                              void* d_out, int out_size, void* d_ws, size_t ws_size,
                              hipStream_t stream) {
    const float* x     = (const float*)d_in[0];
    const int*   ei    = (const int*)d_in[1];
    const float* W_in  = (const float*)d_in[2];
    const float* b_in  = (const float*)d_in[3];
    const float* W_mid = (const float*)d_in[4];
    const float* b_mid = (const float*)d_in[5];
    const float* W_out = (const float*)d_in[6];
    float* out = (float*)d_out;

    const int* srcv = ei;
    const int* dstv = ei + N_EDGES;

    char* w = (char*)d_ws;
    float* dinv   = (float*)(w);                              // 400 KB
    int2* rowse   = (int2*)(w + (1ull << 19));                // 800 KB
    int* bcnt     = (int*)(w + 1507328);                      // 2 KB
    int* colidx   = (int*)(w + (2ull << 20));                 // 7.2 MB
    unsigned int* ebuf = (unsigned int*)(w + (10ull << 20));  // 7.2 MB
    _Float16* Wt  = (_Float16*)(w + (18ull << 20));           // 155 KB
    _Float16* bufA = (_Float16*)(w + (19ull << 20));          // (N+1)*128 fp16, row-major
    _Float16* bufB = (_Float16*)(w + (45ull << 20));          // (N+1)*128 fp16, row-major
    _Float16* zbuf = (_Float16*)(w + (71ull << 20));          // (N+1)*64 fp16
    _Float16* bufC = (_Float16*)(w + (84ull << 20));          // 8*(N+1)*16 fp16, chunk-major

    _Float16* W1h = Wt;
    _Float16* W1l = Wt + 128 * 128;
    _Float16* W2h = Wt + 2 * 128 * 128;
    _Float16* W2l = Wt + 3 * 128 * 128;
    _Float16* W3h = Wt + 4 * 128 * 128;
    _Float16* W3l = Wt + 4 * 128 * 128 + 48 * 128;

    const int NB_PART = (N_EDGES + 4095) / 4096;  // 391

    // CSR build
    hipMemsetAsync(bcnt, 0, NBUCK * sizeof(int), stream);
    k_zrows<<<1, 256, 0, stream>>>(bufC, bufA, zbuf);
    k_bpart<<<NB_PART, 256, 0, stream>>>(srcv, dstv, bcnt, ebuf);
    k_bucket<<<NBUCK, 256, 0, stream>>>(ebuf, bcnt, rowse, dinv, colidx);

    // weight prep (one launch)
    k_wprep_all<<<(304 * 128 + 255) / 256, 256, 0, stream>>>(W_in, W_mid, W_out, Wt);

    const int AGGC_BLOCKS = 8 * (N_NODES / 32);  // 25000: chunk = blk%8, 32 rows/blk
    const int AGG4_BLOCKS = N_NODES / 16;        // 6250
    const int AGGO_BLOCKS = N_NODES / 32;        // 3125

    // Layer 1: fp32 x -> chunk-major bufC; XCD-pinned chunked aggregate -> bufB
    k_gemm128_f32<<<GEMM_GRID, 256, 0, stream>>>(x, W1h, W1l, dinv, bufC);
    k_aggc<<<AGGC_BLOCKS, 256, 0, stream>>>(bufC, rowse, colidx, b_in, bufB);
    // Layer 2: row-major control path
    k_gemm128<<<GEMM_GRID, 256, 0, stream>>>(bufB, W2h, W2l, dinv, bufA);
    k_agg4<<<AGG4_BLOCKS, 256, 0, stream>>>(bufA, rowse, colidx, b_mid, bufB);
    // Layer 3 + fused log_softmax
    k_gemm40<<<G40_GRID, 256, 0, stream>>>(bufB, W3h, W3l, dinv, zbuf);
    k_agg_out<<<AGGO_BLOCKS, 256, 0, stream>>>(zbuf, rowse, colidx, out);
}

// Round 10
// 373.501 us; speedup vs baseline: 1.0716x; 1.0716x over previous
//
#include <hip/hip_runtime.h>
#include <math.h>

#define N_NODES 100000
#define N_EDGES 1600000
#define NBUCK 391          // ceil(100000 / 256)
#define BSTRIDE 4608       // bucket slack stride: mean 4096 + 8 sigma

typedef __attribute__((ext_vector_type(8))) _Float16 h8v;
typedef __attribute__((ext_vector_type(4))) float f32x4;

// ---------------- CSR build: 2 kernels + 1 memset ----------------

__launch_bounds__(256)
__global__ void k_bpart(const int* __restrict__ srcv, const int* __restrict__ dstv,
                        int* __restrict__ bcnt, unsigned int* __restrict__ ebuf) {
    __shared__ int hist[NBUCK];
    __shared__ int cur[NBUCK];
    const int tid = threadIdx.x;
    for (int t = tid; t < NBUCK; t += 256) hist[t] = 0;
    __syncthreads();
    const int base = blockIdx.x * 4096;
#pragma unroll
    for (int i = 0; i < 16; i++) {
        int e = base + i * 256 + tid;
        if (e < N_EDGES) atomicAdd(&hist[dstv[e] >> 8], 1);
    }
    __syncthreads();
    for (int t = tid; t < NBUCK; t += 256)
        if (hist[t]) cur[t] = t * BSTRIDE + atomicAdd(&bcnt[t], hist[t]);
    __syncthreads();
#pragma unroll
    for (int i = 0; i < 16; i++) {
        int e = base + i * 256 + tid;
        if (e < N_EDGES) {
            int d = dstv[e];
            int p = atomicAdd(&cur[d >> 8], 1);
            ebuf[p] = ((unsigned int)srcv[e] << 8) | (unsigned int)(d & 255);
        }
    }
}

__launch_bounds__(256)
__global__ void k_bucket(const unsigned int* __restrict__ ebuf, const int* __restrict__ bcnt,
                         int2* __restrict__ rowse, float* __restrict__ dinv,
                         int* __restrict__ colidx) {
    __shared__ int cnt[256];
    __shared__ int s[256];
    __shared__ int cur[256];
    const int tid = threadIdx.x;
    const int b = blockIdx.x;
    const int e0 = b * BSTRIDE;
    const int e1 = e0 + bcnt[b];
    cnt[tid] = 0;
    __syncthreads();
    for (int e = e0 + tid; e < e1; e += 256) atomicAdd(&cnt[ebuf[e] & 255u], 1);
    __syncthreads();
    int v = cnt[tid];
    int x = v;
    s[tid] = x;
    __syncthreads();
    for (int d = 1; d < 256; d <<= 1) {
        int t = (tid >= d) ? s[tid - d] : 0;
        __syncthreads();
        x += t;
        s[tid] = x;
        __syncthreads();
    }
    int start = e0 + x - v;
    int node = b * 256 + tid;
    if (node < N_NODES) {
        rowse[node] = make_int2(start, start + v);
        dinv[node] = rsqrtf((float)(v + 1));  // +1 self-loop
    }
    cur[tid] = start;
    __syncthreads();
    for (int e = e0 + tid; e < e1; e += 256) {
        unsigned int sd = ebuf[e];
        int pos = atomicAdd(&cur[sd & 255u], 1);
        colidx[pos] = (int)(sd >> 8);
    }
}

// ---------------- fused weight prep + sentinel zeroing ----------------

__global__ void k_prep(const float* __restrict__ W1, const float* __restrict__ W2,
                       const float* __restrict__ W3, _Float16* __restrict__ Wt,
                       _Float16* __restrict__ bufA, _Float16* __restrict__ zbuf) {
    int idx = blockIdx.x * blockDim.x + threadIdx.x;
    if (idx < 128) bufA[(size_t)N_NODES * 128 + idx] = (_Float16)0.f;
    if (idx < 64)  zbuf[(size_t)N_NODES * 64 + idx] = (_Float16)0.f;
    if (idx >= 304 * 128) return;
    int n = idx / 128, k = idx % 128;
    const float* W;
    int ncols, nloc;
    _Float16 *ph, *pl;
    if (n < 128)      { W = W1; ncols = 128; nloc = n;       ph = Wt;                 pl = Wt + 128 * 128; }
    else if (n < 256) { W = W2; ncols = 128; nloc = n - 128; ph = Wt + 2 * 128 * 128; pl = Wt + 3 * 128 * 128; }
    else              { W = W3; ncols = 40;  nloc = n - 256; ph = Wt + 4 * 128 * 128; pl = Wt + 4 * 128 * 128 + 48 * 128; }
    float v = (nloc < ncols) ? W[k * ncols + nloc] : 0.f;
    _Float16 hi = (_Float16)v;
    _Float16 lo = (_Float16)(v - (float)hi);
    ph[nloc * 128 + k] = hi;
    pl[nloc * 128 + k] = lo;
}

// ---------------- Persistent-B MFMA GEMMs ----------------
// B fragments (hi+lo, 64 VGPRs) loaded once per wave; grid-stride over 32-row
// tiles. 1563 blocks x ~2 tiles: ~24 waves/CU for latency hiding (r8's 625
// blocks gave only ~10).

#define GEMM_GRID 1563
#define NTILES 3125

__launch_bounds__(256, 3)
__global__ void k_gemm128_f32(const float* __restrict__ Af,
                              const _Float16* __restrict__ Wthi, const _Float16* __restrict__ Wtlo,
                              const float* __restrict__ dinv, _Float16* __restrict__ out) {
    const int lane = threadIdx.x & 63;
    const int wi = threadIdx.x >> 6;
    const int nb = wi * 32;
    const int nn = lane & 15;
    const int kq = (lane >> 4) * 8;
    const int quad = lane >> 4;

    h8v bh[4][2], bl[4][2];
#pragma unroll
    for (int c = 0; c < 4; c++)
#pragma unroll
        for (int t = 0; t < 2; t++) {
            int off = (nb + t * 16 + nn) * 128 + c * 32 + kq;
            bh[c][t] = *(const h8v*)(Wthi + off);
            bl[c][t] = *(const h8v*)(Wtlo + off);
        }

    for (int rt = blockIdx.x; rt < NTILES; rt += GEMM_GRID) {
        const int r0 = rt * 32;
        f32x4 acc[2][2] = {};
#pragma unroll
        for (int c = 0; c < 4; c++) {
            h8v a[2];
#pragma unroll
            for (int m = 0; m < 2; m++) {
                const float* p = Af + (size_t)(r0 + m * 16 + nn) * 128 + c * 32 + kq;
                float4 p0 = *(const float4*)p;
                float4 p1 = *(const float4*)(p + 4);
                h8v av = {(_Float16)p0.x, (_Float16)p0.y, (_Float16)p0.z, (_Float16)p0.w,
                          (_Float16)p1.x, (_Float16)p1.y, (_Float16)p1.z, (_Float16)p1.w};
                a[m] = av;
            }
#pragma unroll
            for (int m = 0; m < 2; m++)
#pragma unroll
                for (int t = 0; t < 2; t++) {
                    acc[m][t] = __builtin_amdgcn_mfma_f32_16x16x32_f16(a[m], bh[c][t], acc[m][t], 0, 0, 0);
                    acc[m][t] = __builtin_amdgcn_mfma_f32_16x16x32_f16(a[m], bl[c][t], acc[m][t], 0, 0, 0);
                }
        }
#pragma unroll
        for (int m = 0; m < 2; m++)
#pragma unroll
            for (int reg = 0; reg < 4; reg++) {
                int r = r0 + m * 16 + quad * 4 + reg;
                float dv = dinv[r];
#pragma unroll
                for (int t = 0; t < 2; t++)
                    out[(size_t)r * 128 + nb + t * 16 + nn] = (_Float16)(acc[m][t][reg] * dv);
            }
    }
}

__launch_bounds__(256, 3)
__global__ void k_gemm128(const _Float16* __restrict__ A,
                          const _Float16* __restrict__ Wthi, const _Float16* __restrict__ Wtlo,
                          const float* __restrict__ dinv, _Float16* __restrict__ out) {
    const int lane = threadIdx.x & 63;
    const int wi = threadIdx.x >> 6;
    const int nb = wi * 32;
    const int nn = lane & 15;
    const int kq = (lane >> 4) * 8;
    const int quad = lane >> 4;

    h8v bh[4][2], bl[4][2];
#pragma unroll
    for (int c = 0; c < 4; c++)
#pragma unroll
        for (int t = 0; t < 2; t++) {
            int off = (nb + t * 16 + nn) * 128 + c * 32 + kq;
            bh[c][t] = *(const h8v*)(Wthi + off);
            bl[c][t] = *(const h8v*)(Wtlo + off);
        }

    for (int rt = blockIdx.x; rt < NTILES; rt += GEMM_GRID) {
        const int r0 = rt * 32;
        f32x4 acc[2][2] = {};
#pragma unroll
        for (int c = 0; c < 4; c++) {
            h8v a[2];
#pragma unroll
            for (int m = 0; m < 2; m++)
                a[m] = *(const h8v*)(A + (size_t)(r0 + m * 16 + nn) * 128 + c * 32 + kq);
#pragma unroll
            for (int m = 0; m < 2; m++)
#pragma unroll
                for (int t = 0; t < 2; t++) {
                    acc[m][t] = __builtin_amdgcn_mfma_f32_16x16x32_f16(a[m], bh[c][t], acc[m][t], 0, 0, 0);
                    acc[m][t] = __builtin_amdgcn_mfma_f32_16x16x32_f16(a[m], bl[c][t], acc[m][t], 0, 0, 0);
                }
        }
#pragma unroll
        for (int m = 0; m < 2; m++)
#pragma unroll
            for (int reg = 0; reg < 4; reg++) {
                int r = r0 + m * 16 + quad * 4 + reg;
                float dv = dinv[r];
#pragma unroll
                for (int t = 0; t < 2; t++)
                    out[(size_t)r * 128 + nb + t * 16 + nn] = (_Float16)(acc[m][t][reg] * dv);
            }
    }
}

// Layer-3 GEMM: 40 real cols (48 written) into [N+1][64]-stride buffer.
#define G40_GRID 391

__launch_bounds__(256, 3)
__global__ void k_gemm40(const _Float16* __restrict__ A,
                         const _Float16* __restrict__ Wthi, const _Float16* __restrict__ Wtlo,
                         const float* __restrict__ dinv, _Float16* __restrict__ out) {
    const int lane = threadIdx.x & 63;
    const int wi = threadIdx.x >> 6;
    const int nn = lane & 15;
    const int kq = (lane >> 4) * 8;
    const int quad = lane >> 4;

    h8v bh[4][3], bl[4][3];
#pragma unroll
    for (int c = 0; c < 4; c++)
#pragma unroll
        for (int t = 0; t < 3; t++) {
            int off = (t * 16 + nn) * 128 + c * 32 + kq;
            bh[c][t] = *(const h8v*)(Wthi + off);
            bl[c][t] = *(const h8v*)(Wtlo + off);
        }

    for (int rt = blockIdx.x * 4 + wi; rt < NTILES; rt += G40_GRID * 4) {
        const int r0 = rt * 32;
        f32x4 acc[2][3] = {};
#pragma unroll
        for (int c = 0; c < 4; c++) {
            h8v a[2];
#pragma unroll
            for (int m = 0; m < 2; m++)
                a[m] = *(const h8v*)(A + (size_t)(r0 + m * 16 + nn) * 128 + c * 32 + kq);
#pragma unroll
            for (int m = 0; m < 2; m++)
#pragma unroll
                for (int t = 0; t < 3; t++) {
                    acc[m][t] = __builtin_amdgcn_mfma_f32_16x16x32_f16(a[m], bh[c][t], acc[m][t], 0, 0, 0);
                    acc[m][t] = __builtin_amdgcn_mfma_f32_16x16x32_f16(a[m], bl[c][t], acc[m][t], 0, 0, 0);
                }
        }
#pragma unroll
        for (int m = 0; m < 2; m++)
#pragma unroll
            for (int reg = 0; reg < 4; reg++) {
                int r = r0 + m * 16 + quad * 4 + reg;
                float dv = dinv[r];
#pragma unroll
                for (int t = 0; t < 3; t++)
                    out[(size_t)r * 64 + t * 16 + nn] = (_Float16)(acc[m][t][reg] * dv);
            }
    }
}

// ---------------- Slot-parallel aggregation (F=128) — at its random-line roofline ----------------

__launch_bounds__(256)
__global__ void k_agg4(const _Float16* __restrict__ hp, const int2* __restrict__ rowse,
                       const int* __restrict__ colidx, const float* __restrict__ bias,
                       _Float16* __restrict__ outp) {
    const int lane = threadIdx.x & 63;
    const int wid = (blockIdx.x * blockDim.x + threadIdx.x) >> 6;
    const int rs = lane >> 4;   // row slot 0..3
    const int cp = lane & 15;   // 16B col part
    const int r = wid * 4 + rs;

    const int2 se = rowse[r];
    const int deg = se.y - se.x;
    int m = deg;
    m = max(m, __shfl_xor(m, 16));
    m = max(m, __shfl_xor(m, 32));

    const _Float16* hpc = hp + cp * 8;
    h8v acc = {};
    for (int it = 0; it < m; it += 4) {
        int i0 = se.x + it;
        int s0 = colidx[i0];
        int s1 = colidx[i0 + 1];
        int s2 = colidx[i0 + 2];
        int s3 = colidx[i0 + 3];
        s0 = (it < deg) ? s0 : N_NODES;
        s1 = (it + 1 < deg) ? s1 : N_NODES;
        s2 = (it + 2 < deg) ? s2 : N_NODES;
        s3 = (it + 3 < deg) ? s3 : N_NODES;
        h8v v0 = *(const h8v*)(hpc + (size_t)s0 * 128);
        h8v v1 = *(const h8v*)(hpc + (size_t)s1 * 128);
        h8v v2 = *(const h8v*)(hpc + (size_t)s2 * 128);
        h8v v3 = *(const h8v*)(hpc + (size_t)s3 * 128);
        acc += v0;
        acc += v1;
        acc += v2;
        acc += v3;
    }

    h8v sv = *(const h8v*)(hpc + (size_t)r * 128);  // self-loop
    float dv = rsqrtf((float)(deg + 1));
    const float* bp = bias + cp * 8;
    float4 b0 = *(const float4*)bp;
    float4 b1 = *(const float4*)(bp + 4);
    float bb[8] = {b0.x, b0.y, b0.z, b0.w, b1.x, b1.y, b1.z, b1.w};
    h8v o;
#pragma unroll
    for (int j = 0; j < 8; j++) {
        float s = (float)acc[j] + (float)sv[j];
        o[j] = (_Float16)fmaxf(fmaf(dv, s, bb[j]), 0.f);
    }
    *(h8v*)(outp + (size_t)r * 128 + cp * 8) = o;
}

// ---------------- Final aggregation (64-stride rows) + fused log_softmax ----------------

__launch_bounds__(256)
__global__ void k_agg_out(const _Float16* __restrict__ hp, const int2* __restrict__ rowse,
                          const int* __restrict__ colidx, float* __restrict__ out) {
    const int lane = threadIdx.x & 63;
    const int wid = (blockIdx.x * blockDim.x + threadIdx.x) >> 6;
    const int rs = lane >> 3;   // row slot 0..7
    const int cp = lane & 7;    // 16B col part
    const int r = wid * 8 + rs;

    const int2 se = rowse[r];
    const int deg = se.y - se.x;
    int m = deg;
    m = max(m, __shfl_xor(m, 8));
    m = max(m, __shfl_xor(m, 16));
    m = max(m, __shfl_xor(m, 32));

    const _Float16* hpc = hp + cp * 8;
    h8v acc = {};
    for (int it = 0; it < m; it += 4) {
        int i0 = se.x + it;
        int s0 = colidx[i0];
        int s1 = colidx[i0 + 1];
        int s2 = colidx[i0 + 2];
        int s3 = colidx[i0 + 3];
        s0 = (it < deg) ? s0 : N_NODES;
        s1 = (it + 1 < deg) ? s1 : N_NODES;
        s2 = (it + 2 < deg) ? s2 : N_NODES;
        s3 = (it + 3 < deg) ? s3 : N_NODES;
        h8v v0 = *(const h8v*)(hpc + (size_t)s0 * 64);
        h8v v1 = *(const h8v*)(hpc + (size_t)s1 * 64);
        h8v v2 = *(const h8v*)(hpc + (size_t)s2 * 64);
        h8v v3 = *(const h8v*)(hpc + (size_t)s3 * 64);
        acc += v0;
        acc += v1;
        acc += v2;
        acc += v3;
    }

    h8v sv = *(const h8v*)(hpc + (size_t)r * 64);  // self-loop
    float dv = rsqrtf((float)(deg + 1));
    float z[8];
#pragma unroll
    for (int j = 0; j < 8; j++) z[j] = dv * ((float)acc[j] + (float)sv[j]);

    const bool act = cp < 5;  // cols 0..39
    float pm = -INFINITY;
    if (act) {
#pragma unroll
        for (int j = 0; j < 8; j++) pm = fmaxf(pm, z[j]);
    }
    pm = fmaxf(pm, __shfl_xor(pm, 1));
    pm = fmaxf(pm, __shfl_xor(pm, 2));
    pm = fmaxf(pm, __shfl_xor(pm, 4));
    float pe = 0.f;
    if (act) {
#pragma unroll
        for (int j = 0; j < 8; j++) pe += __expf(z[j] - pm);
    }
    pe += __shfl_xor(pe, 1);
    pe += __shfl_xor(pe, 2);
    pe += __shfl_xor(pe, 4);
    float lse = __logf(pe);
    if (act) {
        float* po = out + (size_t)r * 40 + cp * 8;
        float4 o0 = make_float4(z[0] - pm - lse, z[1] - pm - lse, z[2] - pm - lse, z[3] - pm - lse);
        float4 o1 = make_float4(z[4] - pm - lse, z[5] - pm - lse, z[6] - pm - lse, z[7] - pm - lse);
        *(float4*)po = o0;
        *(float4*)(po + 4) = o1;
    }
}

// ---------------- launch ----------------

extern "C" void kernel_launch(void* const* d_in, const int* in_sizes, int n_in,
                              void* d_out, int out_size, void* d_ws, size_t ws_size,
                              hipStream_t stream) {
    const float* x     = (const float*)d_in[0];
    const int*   ei    = (const int*)d_in[1];
    const float* W_in  = (const float*)d_in[2];
    const float* b_in  = (const float*)d_in[3];
    const float* W_mid = (const float*)d_in[4];
    const float* b_mid = (const float*)d_in[5];
    const float* W_out = (const float*)d_in[6];
    float* out = (float*)d_out;

    const int* srcv = ei;
    const int* dstv = ei + N_EDGES;

    char* w = (char*)d_ws;
    float* dinv   = (float*)(w);                              // 400 KB
    int2* rowse   = (int2*)(w + (1ull << 19));                // 800 KB
    int* bcnt     = (int*)(w + 1507328);                      // 2 KB
    int* colidx   = (int*)(w + (2ull << 20));                 // 7.2 MB
    unsigned int* ebuf = (unsigned int*)(w + (10ull << 20));  // 7.2 MB
    _Float16* Wt  = (_Float16*)(w + (18ull << 20));           // 155 KB
    _Float16* bufA = (_Float16*)(w + (19ull << 20));          // (N+1)*128 fp16
    _Float16* bufB = (_Float16*)(w + (45ull << 20));          // (N+1)*128 fp16
    _Float16* zbuf = (_Float16*)(w + (71ull << 20));          // (N+1)*64 fp16

    _Float16* W1h = Wt;
    _Float16* W1l = Wt + 128 * 128;
    _Float16* W2h = Wt + 2 * 128 * 128;
    _Float16* W2l = Wt + 3 * 128 * 128;
    _Float16* W3h = Wt + 4 * 128 * 128;
    _Float16* W3l = Wt + 4 * 128 * 128 + 48 * 128;

    const int NB_PART = (N_EDGES + 4095) / 4096;  // 391

    // CSR build
    hipMemsetAsync(bcnt, 0, NBUCK * sizeof(int), stream);
    k_bpart<<<NB_PART, 256, 0, stream>>>(srcv, dstv, bcnt, ebuf);
    k_bucket<<<NBUCK, 256, 0, stream>>>(ebuf, bcnt, rowse, dinv, colidx);

    // weight prep + sentinel zero (one launch)
    k_prep<<<(304 * 128 + 255) / 256, 256, 0, stream>>>(W_in, W_mid, W_out, Wt, bufA, zbuf);

    const int AGG4_BLOCKS = N_NODES / 16;   // 6250
    const int AGGO_BLOCKS = N_NODES / 32;   // 3125

    // Layer 1 (reads fp32 x directly)
    k_gemm128_f32<<<GEMM_GRID, 256, 0, stream>>>(x, W1h, W1l, dinv, bufA);
    k_agg4<<<AGG4_BLOCKS, 256, 0, stream>>>(bufA, rowse, colidx, b_in, bufB);
    // Layer 2
    k_gemm128<<<GEMM_GRID, 256, 0, stream>>>(bufB, W2h, W2l, dinv, bufA);
    k_agg4<<<AGG4_BLOCKS, 256, 0, stream>>>(bufA, rowse, colidx, b_mid, bufB);
    // Layer 3 + fused log_softmax
    k_gemm40<<<G40_GRID, 256, 0, stream>>>(bufB, W3h, W3l, dinv, zbuf);
    k_agg_out<<<AGGO_BLOCKS, 256, 0, stream>>>(zbuf, rowse, colidx, out);
}